// Round 11
// baseline (388.433 us; speedup 1.0000x reference)
//
#include <hip/hip_runtime.h>

#define N_NODES 50000
#define N_EDGES 1250000
#define EMBED 64
#define N_PAIRS (1024 * 100)
#define BSHIFT 7
#define BSIZE 128
#define NBUCK 391      // ceil(50000/128)
#define CB 153         // edge blocks (8192 edges each)
#define LDS_CAP 4096   // bucket edge capacity (mean 3200, sd 57)
#define GEMV_BLKS ((N_NODES + 63) / 64)   // 782
#define AGG_BLKS (N_NODES / 4)            // 12500
#define AGG_DUP 3                         // diagnostic: 3x idempotent duplication

__device__ inline float bf2f(unsigned short u) {
    return __uint_as_float(((unsigned)u) << 16);
}
__device__ inline unsigned short f2bf(float x) {
    unsigned u = __float_as_uint(x);
    u += 0x7FFF + ((u >> 16) & 1);   // round-to-nearest-even
    return (unsigned short)(u >> 16);
}

// ---- pass 1: per-block bucket histogram; counts[bucket][block] + global bucket totals ----
__global__ __launch_bounds__(1024) void hist_kernel(const int* __restrict__ dst,
                                                    int* __restrict__ counts,
                                                    int* __restrict__ btot) {
    __shared__ int hl[NBUCK];
    int t = threadIdx.x, b = blockIdx.x;
    for (int i = t; i < NBUCK; i += 1024) hl[i] = 0;
    __syncthreads();
    #pragma unroll
    for (int rep = 0; rep < 2; ++rep) {
        int i4 = b * 2048 + rep * 1024 + t;
        if (i4 < N_EDGES / 4) {
            int4 d = ((const int4*)dst)[i4];
            atomicAdd(&hl[d.x >> BSHIFT], 1);
            atomicAdd(&hl[d.y >> BSHIFT], 1);
            atomicAdd(&hl[d.z >> BSHIFT], 1);
            atomicAdd(&hl[d.w >> BSHIFT], 1);
        }
    }
    __syncthreads();
    for (int i = t; i < NBUCK; i += 1024) {
        int v = hl[i];
        counts[i * CB + b] = v;
        if (v) atomicAdd(&btot[i], v);
    }
}

// ---- pass 2a (1 small block): scan 391 bucket totals -> base[] ----
__global__ __launch_bounds__(512) void bscan_kernel(const int* __restrict__ btot,
                                                    int* __restrict__ base) {
    __shared__ int ws[8];
    int t = threadIdx.x, lane = t & 63, wid = t >> 6;
    int v = (t < NBUCK) ? btot[t] : 0;
    int incl = v;
    #pragma unroll
    for (int off = 1; off < 64; off <<= 1) {
        int o = __shfl_up(incl, off);
        if (lane >= off) incl += o;
    }
    if (lane == 63) ws[wid] = incl;
    __syncthreads();
    if (t < 8) {
        int x = ws[t];
        #pragma unroll
        for (int off = 1; off < 8; off <<= 1) {
            int o = __shfl_up(x, off);
            if (t >= off) x += o;
        }
        ws[t] = x;
    }
    __syncthreads();
    int ex = ((wid > 0) ? ws[wid - 1] : 0) + incl - v;
    if (t < NBUCK) base[t] = ex;
    if (t == 0) base[NBUCK] = N_EDGES;
}

// ---- pass 2b: per-bucket wave-scan of its contiguous count row -> offs ----
__global__ __launch_bounds__(64) void offs_kernel(const int* __restrict__ counts,
                                                  const int* __restrict__ base,
                                                  int* __restrict__ offs) {
    int k = blockIdx.x, lane = threadIdx.x;
    const int* rowp = counts + (size_t)k * CB;
    int* orow = offs + (size_t)k * CB;
    int carry = base[k];
    #pragma unroll
    for (int tile = 0; tile < 3; ++tile) {
        int b = tile * 64 + lane;
        int v = (b < CB) ? rowp[b] : 0;
        int incl = v;
        #pragma unroll
        for (int off = 1; off < 64; off <<= 1) {
            int o = __shfl_up(incl, off);
            if (lane >= off) incl += o;
        }
        if (b < CB) orow[b] = carry + incl - v;
        carry += __shfl(incl, 63);
    }
}

// ---- pass 3: scatter edges into bucket-grouped pairs (LDS cursors) ----
__global__ __launch_bounds__(1024) void scatter_kernel(const int* __restrict__ src,
                                                       const int* __restrict__ dst,
                                                       const int* __restrict__ offs,
                                                       unsigned int* __restrict__ pairs) {
    __shared__ int cur[NBUCK];
    int t = threadIdx.x, b = blockIdx.x;
    for (int i = t; i < NBUCK; i += 1024) cur[i] = offs[i * CB + b];
    __syncthreads();
    #pragma unroll
    for (int rep = 0; rep < 2; ++rep) {
        int i4 = b * 2048 + rep * 1024 + t;
        if (i4 < N_EDGES / 4) {
            int4 s4 = ((const int4*)src)[i4];
            int4 d4 = ((const int4*)dst)[i4];
            int p;
            p = atomicAdd(&cur[d4.x >> BSHIFT], 1);
            pairs[p] = ((unsigned)(d4.x & (BSIZE - 1)) << 16) | (unsigned)s4.x;
            p = atomicAdd(&cur[d4.y >> BSHIFT], 1);
            pairs[p] = ((unsigned)(d4.y & (BSIZE - 1)) << 16) | (unsigned)s4.y;
            p = atomicAdd(&cur[d4.z >> BSHIFT], 1);
            pairs[p] = ((unsigned)(d4.z & (BSIZE - 1)) << 16) | (unsigned)s4.z;
            p = atomicAdd(&cur[d4.w >> BSHIFT], 1);
            pairs[p] = ((unsigned)(d4.w & (BSIZE - 1)) << 16) | (unsigned)s4.w;
        }
    }
}

// ---- pass 4 (heterogeneous): blocks 0..NBUCK-1 = per-bucket LDS sort -> row/col;
//      blocks NBUCK.. = dense GEMV g = emb @ W0^T (bf16 out). ----
#define SMEM_BYTES 33808
__global__ __launch_bounds__(256) void sortgemv_kernel(const unsigned int* __restrict__ pairs,
                                                       const int* __restrict__ base,
                                                       int* __restrict__ row,
                                                       int* __restrict__ col,
                                                       const float* __restrict__ emb,
                                                       const float* __restrict__ W,
                                                       unsigned short* __restrict__ g) {
    __shared__ __align__(16) char smem[SMEM_BYTES];
    int t = threadIdx.x;
    if (blockIdx.x < NBUCK) {
        // ---------------- bucketsort path ----------------
        unsigned* ebuf = (unsigned*)smem;             // 4096*4
        int* staged    = (int*)(smem + 16384);        // 4096*4
        int* hist      = (int*)(smem + 32768);        // 128*4
        int* cur       = (int*)(smem + 33280);        // 128*4
        int* wtot      = (int*)(smem + 33792);
        int k = blockIdx.x;
        int lane = t & 63, wid = t >> 6;
        int nstart = k * BSIZE;
        int nodes = min(BSIZE, N_NODES - nstart);
        int estart = base[k], eend = base[k + 1];
        int cnt = eend - estart;
        if (t < BSIZE) hist[t] = 0;
        __syncthreads();
        if (cnt <= LDS_CAP) {
            for (int i = t; i < cnt; i += 256) {
                unsigned w = pairs[estart + i];
                ebuf[i] = w;
                atomicAdd(&hist[w >> 16], 1);
            }
            __syncthreads();
            if (t < BSIZE) {
                int v = hist[t];
                int incl = v;
                #pragma unroll
                for (int off = 1; off < 64; off <<= 1) {
                    int o = __shfl_up(incl, off);
                    if (lane >= off) incl += o;
                }
                if (t == 63) *wtot = incl;
                __syncthreads();
                int ex = incl - v + ((wid == 1) ? *wtot : 0);
                cur[t] = ex;
                if (t < nodes) row[nstart + t] = estart + ex;
            } else {
                __syncthreads();
            }
            if (k == NBUCK - 1 && t == 0) row[N_NODES] = N_EDGES;
            __syncthreads();
            for (int i = t; i < cnt; i += 256) {
                unsigned w = ebuf[i];
                int pos = atomicAdd(&cur[w >> 16], 1);
                staged[pos] = (int)(w & 0xFFFFu);
            }
            __syncthreads();
            for (int i = t; i < cnt; i += 256) col[estart + i] = staged[i];
        } else {   // statistically unreachable fallback
            for (int i = t; i < cnt; i += 256)
                atomicAdd(&hist[pairs[estart + i] >> 16], 1);
            __syncthreads();
            if (t < BSIZE) {
                int v = hist[t];
                int incl = v;
                #pragma unroll
                for (int off = 1; off < 64; off <<= 1) {
                    int o = __shfl_up(incl, off);
                    if (lane >= off) incl += o;
                }
                if (t == 63) *wtot = incl;
                __syncthreads();
                int ex = incl - v + ((wid == 1) ? *wtot : 0);
                cur[t] = ex;
                if (t < nodes) row[nstart + t] = estart + ex;
            } else {
                __syncthreads();
            }
            if (k == NBUCK - 1 && t == 0) row[N_NODES] = N_EDGES;
            __syncthreads();
            for (int i = t; i < cnt; i += 256) {
                unsigned w = pairs[estart + i];
                int pos = atomicAdd(&cur[w >> 16], 1);
                col[estart + pos] = (int)(w & 0xFFFFu);
            }
        }
    } else {
        // ---------------- dense GEMV path (fp32 in, bf16 out) ----------------
        float (*hL)[64] = (float (*)[64])smem;            // 16KB
        float (*Wl)[65] = (float (*)[65])(smem + 16384);  // 16.6KB
        int nstart = (blockIdx.x - NBUCK) * 64;
        int lane = t & 63, wid = t >> 6;
        for (int i = t; i < 4096; i += 256) Wl[i & 63][i >> 6] = W[i];
        int nrem = min(64, N_NODES - nstart);
        for (int i = t; i < nrem * 16; i += 256)
            ((float4*)hL)[i] = ((const float4*)(emb + (size_t)nstart * EMBED))[i];
        __syncthreads();
        for (int n = wid; n < nrem; n += 4) {
            float x = 0.f;
            #pragma unroll
            for (int d = 0; d < 64; ++d)
                x += hL[n][d] * Wl[d][lane];
            g[(size_t)(nstart + n) * EMBED + lane] = f2bf(x);
        }
    }
}

// ---- dense GEMV (bf16 input): g_bf16 = h @ W^T ----
__global__ __launch_bounds__(256) void gemv_bf16_kernel(const unsigned short* __restrict__ h,
                                                        const float* __restrict__ W,
                                                        unsigned short* __restrict__ g) {
    __shared__ float hL[64][64];
    __shared__ float Wl[64][65];
    int t = threadIdx.x;
    int nstart = blockIdx.x * 64;
    int lane = t & 63, wid = t >> 6;
    for (int i = t; i < 4096; i += 256) Wl[i & 63][i >> 6] = W[i];
    int nrem = min(64, N_NODES - nstart);
    for (int i = t; i < nrem * 16; i += 256) {
        ushort4 v = ((const ushort4*)(h + (size_t)nstart * EMBED))[i];
        int r = i >> 4, c = (i & 15) * 4;
        hL[r][c + 0] = bf2f(v.x);
        hL[r][c + 1] = bf2f(v.y);
        hL[r][c + 2] = bf2f(v.z);
        hL[r][c + 3] = bf2f(v.w);
    }
    __syncthreads();
    for (int n = wid; n < nrem; n += 4) {
        float x = 0.f;
        #pragma unroll
        for (int d = 0; d < 64; ++d)
            x += hL[n][d] * Wl[d][lane];
        g[(size_t)(nstart + n) * EMBED + lane] = f2bf(x);
    }
}

// ---- gather-mean + bias + tanh; wave per node, 32 bf16 edges in flight ----
// DIAGNOSTIC (this round): launched with AGG_DUP x grid; node = (blockIdx % AGG_BLKS);
// duplicate blocks recompute and write IDENTICAL values -> idempotent, 3x duration
// makes this dispatch visible in rocprof top-5 with full counters.
__global__ __launch_bounds__(256) void agg_kernel(const unsigned short* __restrict__ g,
                                                  const float* __restrict__ bias,
                                                  const int* __restrict__ row,
                                                  const int* __restrict__ col,
                                                  unsigned short* __restrict__ hout) {
    int t = threadIdx.x;
    int wid = t >> 6, lane = t & 63;
    int node = (blockIdx.x % AGG_BLKS) * 4 + wid;
    int gg = lane >> 4, d16 = lane & 15;
    int start = row[node], end = row[node + 1];
    float4 bb = ((const float4*)bias)[d16];
    float4 acc = {0.f, 0.f, 0.f, 0.f};
    for (int e = start; e < end; e += 32) {
        #pragma unroll
        for (int k = 0; k < 8; ++k) {
            int ee = e + 4 * k + gg;
            if (ee < end) {
                int s = col[ee];
                ushort4 v = ((const ushort4*)(g + (size_t)s * EMBED))[d16];
                acc.x += bf2f(v.x);
                acc.y += bf2f(v.y);
                acc.z += bf2f(v.z);
                acc.w += bf2f(v.w);
            }
        }
    }
    #pragma unroll
    for (int off = 16; off < 64; off <<= 1) {
        acc.x += __shfl_xor(acc.x, off);
        acc.y += __shfl_xor(acc.y, off);
        acc.z += __shfl_xor(acc.z, off);
        acc.w += __shfl_xor(acc.w, off);
    }
    int dg = end - start;
    float inv = (dg > 0) ? 1.0f / (float)dg : 0.f;
    if (gg == 0) {
        ushort4 o;
        o.x = f2bf(tanhf(acc.x * inv + bb.x));
        o.y = f2bf(tanhf(acc.y * inv + bb.y));
        o.z = f2bf(tanhf(acc.z * inv + bb.z));
        o.w = f2bf(tanhf(acc.w * inv + bb.w));
        ((ushort4*)(hout + (size_t)node * EMBED))[d16] = o;
    }
}

// ---- pair scoring: 16 lanes x ushort4 (bf16) per pair ----
__global__ __launch_bounds__(256) void score_kernel(const unsigned short* __restrict__ h,
                                                    const int* __restrict__ ui,
                                                    const int* __restrict__ ii,
                                                    float* __restrict__ out) {
    int t = threadIdx.x;
    int idx = blockIdx.x * 16 + (t >> 4);
    int d16 = t & 15;
    int u = ui[idx];
    int v = ii[idx];
    ushort4 a4 = ((const ushort4*)(h + (size_t)u * EMBED))[d16];
    ushort4 b4 = ((const ushort4*)(h + (size_t)v * EMBED))[d16];
    float p = bf2f(a4.x) * bf2f(b4.x) + bf2f(a4.y) * bf2f(b4.y) +
              bf2f(a4.z) * bf2f(b4.z) + bf2f(a4.w) * bf2f(b4.w);
    #pragma unroll
    for (int off = 8; off > 0; off >>= 1)
        p += __shfl_xor(p, off);
    if (d16 == 0) out[idx] = p;
}

extern "C" void kernel_launch(void* const* d_in, const int* in_sizes, int n_in,
                              void* d_out, int out_size, void* d_ws, size_t ws_size,
                              hipStream_t stream) {
    const float* emb = (const float*)d_in[0];
    const float* W0  = (const float*)d_in[1];
    const float* b0  = (const float*)d_in[2];
    const float* W1  = (const float*)d_in[3];
    const float* b1  = (const float*)d_in[4];
    const int* src   = (const int*)d_in[5];
    const int* dst   = (const int*)d_in[6];
    const int* ui    = (const int*)d_in[7];
    const int* ii    = (const int*)d_in[8];
    float* out = (float*)d_out;

    char* p = (char*)d_ws;
    auto alloc = [&](size_t bytes) {
        char* r = p;
        p += (bytes + 255) & ~(size_t)255;
        return r;
    };
    int* counts          = (int*)alloc(sizeof(int) * NBUCK * CB);
    int* offs            = (int*)alloc(sizeof(int) * NBUCK * CB);
    int* btot            = (int*)alloc(sizeof(int) * NBUCK);
    int* base            = (int*)alloc(sizeof(int) * (NBUCK + 1));
    int* row             = (int*)alloc(sizeof(int) * (N_NODES + 1));
    unsigned* pairs      = (unsigned*)alloc(sizeof(unsigned) * N_EDGES);
    int* col             = (int*)alloc(sizeof(int) * N_EDGES);
    unsigned short* gbuf = (unsigned short*)alloc(sizeof(unsigned short) * N_NODES * EMBED);
    unsigned short* hbuf = (unsigned short*)alloc(sizeof(unsigned short) * N_NODES * EMBED);

    hipMemsetAsync(btot, 0, sizeof(int) * NBUCK, stream);
    hist_kernel<<<CB, 1024, 0, stream>>>(dst, counts, btot);
    bscan_kernel<<<1, 512, 0, stream>>>(btot, base);
    offs_kernel<<<NBUCK, 64, 0, stream>>>(counts, base, offs);
    scatter_kernel<<<CB, 1024, 0, stream>>>(src, dst, offs, pairs);
    // bucketsort (391 blocks) overlapped with layer-1 GEMV (782 blocks)
    sortgemv_kernel<<<NBUCK + GEMV_BLKS, 256, 0, stream>>>(pairs, base, row, col,
                                                           emb, W0, gbuf);
    // DIAGNOSTIC: 3x duplicated grids (idempotent) to surface agg in rocprof top-5
    agg_kernel<<<AGG_BLKS * AGG_DUP, 256, 0, stream>>>(gbuf, b0, row, col, hbuf);
    gemv_bf16_kernel<<<GEMV_BLKS, 256, 0, stream>>>(hbuf, W1, gbuf);
    agg_kernel<<<AGG_BLKS * AGG_DUP, 256, 0, stream>>>(gbuf, b1, row, col, hbuf);
    score_kernel<<<N_PAIRS / 16, 256, 0, stream>>>(hbuf, ui, ii, out);
}

// Round 12
// 240.347 us; speedup vs baseline: 1.6161x; 1.6161x over previous
//
#include <hip/hip_runtime.h>

#define N_NODES 50000
#define N_EDGES 1250000
#define EMBED 64
#define N_PAIRS (1024 * 100)
#define BSHIFT 7
#define BSIZE 128
#define NBUCK 391      // ceil(50000/128)
#define CB 153         // edge blocks (8192 edges each)
#define LDS_CAP 4096
#define FAST_MAX 3584  // fast-path gate: cnt<=3584 -> padded total <=4096 (bucket mean 3200, sd 57)
#define CAP 4096       // per-bucket col capacity (padded, bucket-strided)
#define GEMV_BLKS ((N_NODES + 63) / 64)   // 782

// ---- pass 1: per-block bucket histogram; counts[bucket][block] + global bucket totals ----
__global__ __launch_bounds__(1024) void hist_kernel(const int* __restrict__ dst,
                                                    int* __restrict__ counts,
                                                    int* __restrict__ btot) {
    __shared__ int hl[NBUCK];
    int t = threadIdx.x, b = blockIdx.x;
    for (int i = t; i < NBUCK; i += 1024) hl[i] = 0;
    __syncthreads();
    #pragma unroll
    for (int rep = 0; rep < 2; ++rep) {
        int i4 = b * 2048 + rep * 1024 + t;
        if (i4 < N_EDGES / 4) {
            int4 d = ((const int4*)dst)[i4];
            atomicAdd(&hl[d.x >> BSHIFT], 1);
            atomicAdd(&hl[d.y >> BSHIFT], 1);
            atomicAdd(&hl[d.z >> BSHIFT], 1);
            atomicAdd(&hl[d.w >> BSHIFT], 1);
        }
    }
    __syncthreads();
    for (int i = t; i < NBUCK; i += 1024) {
        int v = hl[i];
        counts[i * CB + b] = v;
        if (v) atomicAdd(&btot[i], v);
    }
}

// ---- pass 2a (1 small block): scan 391 bucket totals -> base[] ----
__global__ __launch_bounds__(512) void bscan_kernel(const int* __restrict__ btot,
                                                    int* __restrict__ base) {
    __shared__ int ws[8];
    int t = threadIdx.x, lane = t & 63, wid = t >> 6;
    int v = (t < NBUCK) ? btot[t] : 0;
    int incl = v;
    #pragma unroll
    for (int off = 1; off < 64; off <<= 1) {
        int o = __shfl_up(incl, off);
        if (lane >= off) incl += o;
    }
    if (lane == 63) ws[wid] = incl;
    __syncthreads();
    if (t < 8) {
        int x = ws[t];
        #pragma unroll
        for (int off = 1; off < 8; off <<= 1) {
            int o = __shfl_up(x, off);
            if (t >= off) x += o;
        }
        ws[t] = x;
    }
    __syncthreads();
    int ex = ((wid > 0) ? ws[wid - 1] : 0) + incl - v;
    if (t < NBUCK) base[t] = ex;
    if (t == 0) base[NBUCK] = N_EDGES;
}

// ---- pass 2b: per-bucket wave-scan of its contiguous count row -> offs ----
__global__ __launch_bounds__(64) void offs_kernel(const int* __restrict__ counts,
                                                  const int* __restrict__ base,
                                                  int* __restrict__ offs) {
    int k = blockIdx.x, lane = threadIdx.x;
    const int* rowp = counts + (size_t)k * CB;
    int* orow = offs + (size_t)k * CB;
    int carry = base[k];
    #pragma unroll
    for (int tile = 0; tile < 3; ++tile) {
        int b = tile * 64 + lane;
        int v = (b < CB) ? rowp[b] : 0;
        int incl = v;
        #pragma unroll
        for (int off = 1; off < 64; off <<= 1) {
            int o = __shfl_up(incl, off);
            if (lane >= off) incl += o;
        }
        if (b < CB) orow[b] = carry + incl - v;
        carry += __shfl(incl, 63);
    }
}

// ---- pass 3: scatter edges into bucket-grouped pairs (LDS cursors) ----
__global__ __launch_bounds__(1024) void scatter_kernel(const int* __restrict__ src,
                                                       const int* __restrict__ dst,
                                                       const int* __restrict__ offs,
                                                       unsigned int* __restrict__ pairs) {
    __shared__ int cur[NBUCK];
    int t = threadIdx.x, b = blockIdx.x;
    for (int i = t; i < NBUCK; i += 1024) cur[i] = offs[i * CB + b];
    __syncthreads();
    #pragma unroll
    for (int rep = 0; rep < 2; ++rep) {
        int i4 = b * 2048 + rep * 1024 + t;
        if (i4 < N_EDGES / 4) {
            int4 s4 = ((const int4*)src)[i4];
            int4 d4 = ((const int4*)dst)[i4];
            int p;
            p = atomicAdd(&cur[d4.x >> BSHIFT], 1);
            pairs[p] = ((unsigned)(d4.x & (BSIZE - 1)) << 16) | (unsigned)s4.x;
            p = atomicAdd(&cur[d4.y >> BSHIFT], 1);
            pairs[p] = ((unsigned)(d4.y & (BSIZE - 1)) << 16) | (unsigned)s4.y;
            p = atomicAdd(&cur[d4.z >> BSHIFT], 1);
            pairs[p] = ((unsigned)(d4.z & (BSIZE - 1)) << 16) | (unsigned)s4.z;
            p = atomicAdd(&cur[d4.w >> BSHIFT], 1);
            pairs[p] = ((unsigned)(d4.w & (BSIZE - 1)) << 16) | (unsigned)s4.w;
        }
    }
}

// ---- pass 4 (heterogeneous): blocks 0..NBUCK-1 = per-bucket sort -> PADDED col
//      (bucket-strided, CAP slots/bucket; rows padded to mult of 4 with dummy
//      src = N_NODES) + rowp[] + degv[]; blocks NBUCK.. = dense GEMV
//      g = emb @ W0^T (fp32), last GEMV block also zeros pad row g[N_NODES]. ----
#define SMEM_BYTES 34832
__global__ __launch_bounds__(256) void sortgemv_kernel(const unsigned int* __restrict__ pairs,
                                                       const int* __restrict__ base,
                                                       int* __restrict__ rowp,
                                                       int* __restrict__ degv,
                                                       int* __restrict__ col,
                                                       const float* __restrict__ emb,
                                                       const float* __restrict__ W,
                                                       float* __restrict__ g) {
    __shared__ __align__(16) char smem[SMEM_BYTES];
    int t = threadIdx.x;
    if (blockIdx.x < NBUCK) {
        // ---------------- bucketsort path ----------------
        unsigned* ebuf = (unsigned*)smem;             // 4096*4 = 16KB
        int* staged    = (int*)(smem + 16384);        // 4096*4 = 16KB
        int* hist      = (int*)(smem + 32768);        // 128*4
        int* cur       = (int*)(smem + 33280);        // 128*4
        int* wtot      = (int*)(smem + 33792);
        int* ptotS     = (int*)(smem + 33796);
        int k = blockIdx.x;
        int lane = t & 63, wid = t >> 6;
        int nstart = k * BSIZE;
        int nodes = min(BSIZE, N_NODES - nstart);
        int estart = base[k], eend = base[k + 1];
        int cnt = eend - estart;
        int cbase = k << 12;   // k * CAP
        if (t < BSIZE) hist[t] = 0;
        __syncthreads();
        if (cnt <= FAST_MAX) {
            for (int i = t; i < cnt; i += 256) {
                unsigned w = pairs[estart + i];
                ebuf[i] = w;
                atomicAdd(&hist[w >> 16], 1);
            }
            __syncthreads();
            if (t < BSIZE) {                 // padded scan over 128 counters (2 waves)
                int dgv = hist[t];
                int pd = (dgv + 3) & ~3;     // pad row to multiple of 4
                int incl = pd;
                #pragma unroll
                for (int off = 1; off < 64; off <<= 1) {
                    int o = __shfl_up(incl, off);
                    if (lane >= off) incl += o;
                }
                if (t == 63) *wtot = incl;
                __syncthreads();
                int ex = incl - pd + ((wid == 1) ? *wtot : 0);
                cur[t] = ex;
                if (t == BSIZE - 1) *ptotS = ex + pd;
                if (t < nodes) {
                    rowp[nstart + t] = cbase + ex;
                    degv[nstart + t] = dgv;
                }
            } else {
                __syncthreads();
            }
            __syncthreads();
            int ptot = *ptotS;
            for (int i = t; i < ptot; i += 256) staged[i] = N_NODES;  // dummy init
            __syncthreads();
            for (int i = t; i < cnt; i += 256) {
                unsigned w = ebuf[i];
                int pos = atomicAdd(&cur[w >> 16], 1);
                staged[pos] = (int)(w & 0xFFFFu);
            }
            __syncthreads();
            for (int i = t; i < ptot; i += 256) col[cbase + i] = staged[i];
        } else {   // statistically unreachable fallback (global, no LDS staging)
            for (int i = t; i < cnt; i += 256)
                atomicAdd(&hist[pairs[estart + i] >> 16], 1);
            __syncthreads();
            if (t < BSIZE) {
                int dgv = hist[t];
                int pd = (dgv + 3) & ~3;
                int incl = pd;
                #pragma unroll
                for (int off = 1; off < 64; off <<= 1) {
                    int o = __shfl_up(incl, off);
                    if (lane >= off) incl += o;
                }
                if (t == 63) *wtot = incl;
                __syncthreads();
                int ex = incl - pd + ((wid == 1) ? *wtot : 0);
                cur[t] = ex;
                if (t == BSIZE - 1) *ptotS = ex + pd;
                if (t < nodes) {
                    rowp[nstart + t] = cbase + ex;
                    degv[nstart + t] = dgv;
                }
            } else {
                __syncthreads();
            }
            __syncthreads();
            int ptot = *ptotS;
            for (int i = t; i < ptot; i += 256) col[cbase + i] = N_NODES;
            __syncthreads();
            for (int i = t; i < cnt; i += 256) {
                unsigned w = pairs[estart + i];
                int pos = atomicAdd(&cur[w >> 16], 1);
                col[cbase + pos] = (int)(w & 0xFFFFu);
            }
        }
    } else {
        // ---------------- dense GEMV path (fp32): g = emb @ W^T ----------------
        float (*hL)[64] = (float (*)[64])smem;            // 16KB
        float (*Wl)[65] = (float (*)[65])(smem + 16384);  // 16.6KB
        int gb = blockIdx.x - NBUCK;
        int nstart = gb * 64;
        int lane = t & 63, wid = t >> 6;
        for (int i = t; i < 4096; i += 256) Wl[i & 63][i >> 6] = W[i];
        int nrem = min(64, N_NODES - nstart);
        for (int i = t; i < nrem * 16; i += 256)
            ((float4*)hL)[i] = ((const float4*)(emb + (size_t)nstart * EMBED))[i];
        // last GEMV block zeros the dummy pad row g[N_NODES]
        if (gb == GEMV_BLKS - 1 && t < 64) g[(size_t)N_NODES * EMBED + t] = 0.f;
        __syncthreads();
        for (int n = wid; n < nrem; n += 4) {
            float x = 0.f;
            #pragma unroll
            for (int d = 0; d < 64; ++d)
                x += hL[n][d] * Wl[d][lane];
            g[(size_t)(nstart + n) * EMBED + lane] = x;
        }
    }
}

// ---- dense GEMV (fp32, layer 2): g = h @ W^T; pad row stays zero (not touched) ----
__global__ __launch_bounds__(256) void gemv_kernel(const float* __restrict__ h,
                                                   const float* __restrict__ W,
                                                   float* __restrict__ g) {
    __shared__ float hL[64][64];
    __shared__ float Wl[64][65];
    int t = threadIdx.x;
    int nstart = blockIdx.x * 64;
    int lane = t & 63, wid = t >> 6;
    for (int i = t; i < 4096; i += 256) Wl[i & 63][i >> 6] = W[i];
    int nrem = min(64, N_NODES - nstart);
    for (int i = t; i < nrem * 16; i += 256)
        ((float4*)hL)[i] = ((const float4*)(h + (size_t)nstart * EMBED))[i];
    __syncthreads();
    for (int n = wid; n < nrem; n += 4) {
        float x = 0.f;
        #pragma unroll
        for (int d = 0; d < 64; ++d)
            x += hL[n][d] * Wl[d][lane];
        g[(size_t)(nstart + n) * EMBED + lane] = x;
    }
}

// ---- gather-mean + bias + tanh; wave per node; branch-free padded rows, fp32 ----
__global__ __launch_bounds__(256) void agg_kernel(const float* __restrict__ g,
                                                  const float* __restrict__ bias,
                                                  const int* __restrict__ rowp,
                                                  const int* __restrict__ degv,
                                                  const int* __restrict__ col,
                                                  float* __restrict__ hout) {
    int t = threadIdx.x;
    int wid = t >> 6, lane = t & 63;
    int node = blockIdx.x * 4 + wid;   // grid exactly N_NODES/4
    int gg = lane >> 4, d16 = lane & 15;
    int start = rowp[node];
    int dg = degv[node];
    int pcnt = (dg + 3) & ~3;
    int endp = start + pcnt;
    float4 bb = ((const float4*)bias)[d16];
    float4 acc = {0.f, 0.f, 0.f, 0.f};
    int e = start;
    for (; e + 8 <= endp; e += 8) {      // 2 gathers in flight, no lane masks
        int s0 = col[e + gg];
        int s1 = col[e + 4 + gg];
        float4 v0 = ((const float4*)(g + (size_t)s0 * EMBED))[d16];
        float4 v1 = ((const float4*)(g + (size_t)s1 * EMBED))[d16];
        acc.x += v0.x + v1.x;
        acc.y += v0.y + v1.y;
        acc.z += v0.z + v1.z;
        acc.w += v0.w + v1.w;
    }
    if (e < endp) {                       // one remaining 4-slot group
        int s0 = col[e + gg];
        float4 v0 = ((const float4*)(g + (size_t)s0 * EMBED))[d16];
        acc.x += v0.x; acc.y += v0.y; acc.z += v0.z; acc.w += v0.w;
    }
    #pragma unroll
    for (int off = 16; off < 64; off <<= 1) {
        acc.x += __shfl_xor(acc.x, off);
        acc.y += __shfl_xor(acc.y, off);
        acc.z += __shfl_xor(acc.z, off);
        acc.w += __shfl_xor(acc.w, off);
    }
    float inv = (dg > 0) ? 1.0f / (float)dg : 0.f;
    if (gg == 0) {
        float4 o;
        o.x = tanhf(acc.x * inv + bb.x);
        o.y = tanhf(acc.y * inv + bb.y);
        o.z = tanhf(acc.z * inv + bb.z);
        o.w = tanhf(acc.w * inv + bb.w);
        ((float4*)(hout + (size_t)node * EMBED))[d16] = o;
    }
}

// ---- pair scoring: 16 lanes x float4 per pair ----
__global__ __launch_bounds__(256) void score_kernel(const float* __restrict__ h,
                                                    const int* __restrict__ ui,
                                                    const int* __restrict__ ii,
                                                    float* __restrict__ out) {
    int t = threadIdx.x;
    int idx = blockIdx.x * 16 + (t >> 4);
    int d16 = t & 15;
    int u = ui[idx];
    int v = ii[idx];
    float4 a = ((const float4*)(h + (size_t)u * EMBED))[d16];
    float4 b = ((const float4*)(h + (size_t)v * EMBED))[d16];
    float p = a.x * b.x + a.y * b.y + a.z * b.z + a.w * b.w;
    #pragma unroll
    for (int off = 8; off > 0; off >>= 1)
        p += __shfl_xor(p, off);
    if (d16 == 0) out[idx] = p;
}

extern "C" void kernel_launch(void* const* d_in, const int* in_sizes, int n_in,
                              void* d_out, int out_size, void* d_ws, size_t ws_size,
                              hipStream_t stream) {
    const float* emb = (const float*)d_in[0];
    const float* W0  = (const float*)d_in[1];
    const float* b0  = (const float*)d_in[2];
    const float* W1  = (const float*)d_in[3];
    const float* b1  = (const float*)d_in[4];
    const int* src   = (const int*)d_in[5];
    const int* dst   = (const int*)d_in[6];
    const int* ui    = (const int*)d_in[7];
    const int* ii    = (const int*)d_in[8];
    float* out = (float*)d_out;

    char* p = (char*)d_ws;
    auto alloc = [&](size_t bytes) {
        char* r = p;
        p += (bytes + 255) & ~(size_t)255;
        return r;
    };
    int* counts     = (int*)alloc(sizeof(int) * NBUCK * CB);
    int* offs       = (int*)alloc(sizeof(int) * NBUCK * CB);
    int* btot       = (int*)alloc(sizeof(int) * NBUCK);
    int* base       = (int*)alloc(sizeof(int) * (NBUCK + 1));
    int* rowp       = (int*)alloc(sizeof(int) * N_NODES);
    int* degv       = (int*)alloc(sizeof(int) * N_NODES);
    unsigned* pairs = (unsigned*)alloc(sizeof(unsigned) * N_EDGES);
    int* col        = (int*)alloc(sizeof(int) * NBUCK * CAP);
    float* gbuf     = (float*)alloc(sizeof(float) * (N_NODES + 1) * EMBED);  // +1 zero pad row
    float* hbuf     = (float*)alloc(sizeof(float) * N_NODES * EMBED);

    hipMemsetAsync(btot, 0, sizeof(int) * NBUCK, stream);
    hist_kernel<<<CB, 1024, 0, stream>>>(dst, counts, btot);
    bscan_kernel<<<1, 512, 0, stream>>>(btot, base);
    offs_kernel<<<NBUCK, 64, 0, stream>>>(counts, base, offs);
    scatter_kernel<<<CB, 1024, 0, stream>>>(src, dst, offs, pairs);
    // bucketsort (391 blocks, padded col) overlapped with layer-1 GEMV (782 blocks)
    sortgemv_kernel<<<NBUCK + GEMV_BLKS, 256, 0, stream>>>(pairs, base, rowp, degv, col,
                                                           emb, W0, gbuf);
    agg_kernel<<<N_NODES / 4, 256, 0, stream>>>(gbuf, b0, rowp, degv, col, hbuf);
    gemv_kernel<<<GEMV_BLKS, 256, 0, stream>>>(hbuf, W1, gbuf);
    agg_kernel<<<N_NODES / 4, 256, 0, stream>>>(gbuf, b1, rowp, degv, col, hbuf);
    score_kernel<<<N_PAIRS / 16, 256, 0, stream>>>(hbuf, ui, ii, out);
}

// Round 13
// 220.660 us; speedup vs baseline: 1.7603x; 1.0892x over previous
//
#include <hip/hip_runtime.h>

#define N_NODES 50000
#define N_EDGES 1250000
#define EMBED 64
#define N_PAIRS (1024 * 100)
#define BSHIFT 7
#define BSIZE 128
#define NBUCK 391      // ceil(50000/128)
#define CB 153         // edge blocks (8192 edges each)
#define FAST_MAX 3584  // fast path: padded total <=4096 (bucket mean 3200, sd 57)
#define CAP 4096       // per-bucket col capacity (padded, bucket-strided)
#define GEMV_BLKS ((N_NODES + 63) / 64)   // 782

__device__ inline float bf2f(unsigned short u) {
    return __uint_as_float(((unsigned)u) << 16);
}
__device__ inline unsigned short f2bf(float x) {
    unsigned u = __float_as_uint(x);
    u += 0x7FFF + ((u >> 16) & 1);   // round-to-nearest-even
    return (unsigned short)(u >> 16);
}

// ---- pass 1: per-block bucket histogram; counts[bucket][block] + global bucket totals ----
__global__ __launch_bounds__(1024) void hist_kernel(const int* __restrict__ dst,
                                                    int* __restrict__ counts,
                                                    int* __restrict__ btot) {
    __shared__ int hl[NBUCK];
    int t = threadIdx.x, b = blockIdx.x;
    for (int i = t; i < NBUCK; i += 1024) hl[i] = 0;
    __syncthreads();
    #pragma unroll
    for (int rep = 0; rep < 2; ++rep) {
        int i4 = b * 2048 + rep * 1024 + t;
        if (i4 < N_EDGES / 4) {
            int4 d = ((const int4*)dst)[i4];
            atomicAdd(&hl[d.x >> BSHIFT], 1);
            atomicAdd(&hl[d.y >> BSHIFT], 1);
            atomicAdd(&hl[d.z >> BSHIFT], 1);
            atomicAdd(&hl[d.w >> BSHIFT], 1);
        }
    }
    __syncthreads();
    for (int i = t; i < NBUCK; i += 1024) {
        int v = hl[i];
        counts[i * CB + b] = v;
        if (v) atomicAdd(&btot[i], v);
    }
}

// ---- pass 2a (1 small block): scan 391 bucket totals -> base[] ----
__global__ __launch_bounds__(512) void bscan_kernel(const int* __restrict__ btot,
                                                    int* __restrict__ base) {
    __shared__ int ws[8];
    int t = threadIdx.x, lane = t & 63, wid = t >> 6;
    int v = (t < NBUCK) ? btot[t] : 0;
    int incl = v;
    #pragma unroll
    for (int off = 1; off < 64; off <<= 1) {
        int o = __shfl_up(incl, off);
        if (lane >= off) incl += o;
    }
    if (lane == 63) ws[wid] = incl;
    __syncthreads();
    if (t < 8) {
        int x = ws[t];
        #pragma unroll
        for (int off = 1; off < 8; off <<= 1) {
            int o = __shfl_up(x, off);
            if (t >= off) x += o;
        }
        ws[t] = x;
    }
    __syncthreads();
    int ex = ((wid > 0) ? ws[wid - 1] : 0) + incl - v;
    if (t < NBUCK) base[t] = ex;
    if (t == 0) base[NBUCK] = N_EDGES;
}

// ---- pass 2b: per-bucket wave-scan of its contiguous count row -> offs ----
__global__ __launch_bounds__(64) void offs_kernel(const int* __restrict__ counts,
                                                  const int* __restrict__ base,
                                                  int* __restrict__ offs) {
    int k = blockIdx.x, lane = threadIdx.x;
    const int* rowp = counts + (size_t)k * CB;
    int* orow = offs + (size_t)k * CB;
    int carry = base[k];
    #pragma unroll
    for (int tile = 0; tile < 3; ++tile) {
        int b = tile * 64 + lane;
        int v = (b < CB) ? rowp[b] : 0;
        int incl = v;
        #pragma unroll
        for (int off = 1; off < 64; off <<= 1) {
            int o = __shfl_up(incl, off);
            if (lane >= off) incl += o;
        }
        if (b < CB) orow[b] = carry + incl - v;
        carry += __shfl(incl, 63);
    }
}

// ---- pass 3: scatter edges into bucket-grouped pairs (LDS cursors) ----
__global__ __launch_bounds__(1024) void scatter_kernel(const int* __restrict__ src,
                                                       const int* __restrict__ dst,
                                                       const int* __restrict__ offs,
                                                       unsigned int* __restrict__ pairs) {
    __shared__ int cur[NBUCK];
    int t = threadIdx.x, b = blockIdx.x;
    for (int i = t; i < NBUCK; i += 1024) cur[i] = offs[i * CB + b];
    __syncthreads();
    #pragma unroll
    for (int rep = 0; rep < 2; ++rep) {
        int i4 = b * 2048 + rep * 1024 + t;
        if (i4 < N_EDGES / 4) {
            int4 s4 = ((const int4*)src)[i4];
            int4 d4 = ((const int4*)dst)[i4];
            int p;
            p = atomicAdd(&cur[d4.x >> BSHIFT], 1);
            pairs[p] = ((unsigned)(d4.x & (BSIZE - 1)) << 16) | (unsigned)s4.x;
            p = atomicAdd(&cur[d4.y >> BSHIFT], 1);
            pairs[p] = ((unsigned)(d4.y & (BSIZE - 1)) << 16) | (unsigned)s4.y;
            p = atomicAdd(&cur[d4.z >> BSHIFT], 1);
            pairs[p] = ((unsigned)(d4.z & (BSIZE - 1)) << 16) | (unsigned)s4.z;
            p = atomicAdd(&cur[d4.w >> BSHIFT], 1);
            pairs[p] = ((unsigned)(d4.w & (BSIZE - 1)) << 16) | (unsigned)s4.w;
        }
    }
}

// ---- pass 4 (heterogeneous): blocks 0..NBUCK-1 = per-bucket sort -> PADDED col
//      + rowp[] + degv[]; blocks NBUCK.. = dense GEMV g = emb @ W0^T (bf16 out),
//      last GEMV block zeros pad row g[N_NODES]. ----
#define SMEM_BYTES 34832
__global__ __launch_bounds__(256) void sortgemv_kernel(const unsigned int* __restrict__ pairs,
                                                       const int* __restrict__ base,
                                                       int* __restrict__ rowp,
                                                       int* __restrict__ degv,
                                                       int* __restrict__ col,
                                                       const float* __restrict__ emb,
                                                       const float* __restrict__ W,
                                                       unsigned short* __restrict__ g) {
    __shared__ __align__(16) char smem[SMEM_BYTES];
    int t = threadIdx.x;
    if (blockIdx.x < NBUCK) {
        // ---------------- bucketsort path ----------------
        unsigned* ebuf = (unsigned*)smem;             // 16KB
        int* staged    = (int*)(smem + 16384);        // 16KB
        int* hist      = (int*)(smem + 32768);        // 512B
        int* cur       = (int*)(smem + 33280);        // 512B
        int* wtot      = (int*)(smem + 33792);
        int* ptotS     = (int*)(smem + 33796);
        int k = blockIdx.x;
        int lane = t & 63, wid = t >> 6;
        int nstart = k * BSIZE;
        int nodes = min(BSIZE, N_NODES - nstart);
        int estart = base[k], eend = base[k + 1];
        int cnt = eend - estart;
        int cbase = k << 12;   // k * CAP
        if (t < BSIZE) hist[t] = 0;
        __syncthreads();
        if (cnt <= FAST_MAX) {
            for (int i = t; i < cnt; i += 256) {
                unsigned w = pairs[estart + i];
                ebuf[i] = w;
                atomicAdd(&hist[w >> 16], 1);
            }
            __syncthreads();
            if (t < BSIZE) {                 // padded scan over 128 counters
                int dgv = hist[t];
                int pd = (dgv + 3) & ~3;     // pad row to multiple of 4
                int incl = pd;
                #pragma unroll
                for (int off = 1; off < 64; off <<= 1) {
                    int o = __shfl_up(incl, off);
                    if (lane >= off) incl += o;
                }
                if (t == 63) *wtot = incl;
                __syncthreads();
                int ex = incl - pd + ((wid == 1) ? *wtot : 0);
                cur[t] = ex;
                if (t == BSIZE - 1) *ptotS = ex + pd;
                if (t < nodes) {
                    rowp[nstart + t] = cbase + ex;
                    degv[nstart + t] = dgv;
                }
            } else {
                __syncthreads();
            }
            __syncthreads();
            int ptot = *ptotS;
            for (int i = t; i < ptot; i += 256) staged[i] = N_NODES;  // dummy init
            __syncthreads();
            for (int i = t; i < cnt; i += 256) {
                unsigned w = ebuf[i];
                int pos = atomicAdd(&cur[w >> 16], 1);
                staged[pos] = (int)(w & 0xFFFFu);
            }
            __syncthreads();
            for (int i = t; i < ptot; i += 256) col[cbase + i] = staged[i];
        } else {   // statistically unreachable fallback
            for (int i = t; i < cnt; i += 256)
                atomicAdd(&hist[pairs[estart + i] >> 16], 1);
            __syncthreads();
            if (t < BSIZE) {
                int dgv = hist[t];
                int pd = (dgv + 3) & ~3;
                int incl = pd;
                #pragma unroll
                for (int off = 1; off < 64; off <<= 1) {
                    int o = __shfl_up(incl, off);
                    if (lane >= off) incl += o;
                }
                if (t == 63) *wtot = incl;
                __syncthreads();
                int ex = incl - pd + ((wid == 1) ? *wtot : 0);
                cur[t] = ex;
                if (t == BSIZE - 1) *ptotS = ex + pd;
                if (t < nodes) {
                    rowp[nstart + t] = cbase + ex;
                    degv[nstart + t] = dgv;
                }
            } else {
                __syncthreads();
            }
            __syncthreads();
            int ptot = *ptotS;
            for (int i = t; i < ptot; i += 256) col[cbase + i] = N_NODES;
            __syncthreads();
            for (int i = t; i < cnt; i += 256) {
                unsigned w = pairs[estart + i];
                int pos = atomicAdd(&cur[w >> 16], 1);
                col[cbase + pos] = (int)(w & 0xFFFFu);
            }
        }
    } else {
        // ---------------- dense GEMV path (fp32 in, bf16 out) ----------------
        float (*hL)[64] = (float (*)[64])smem;            // 16KB
        float (*Wl)[65] = (float (*)[65])(smem + 16384);  // 16.6KB
        int gb = blockIdx.x - NBUCK;
        int nstart = gb * 64;
        int lane = t & 63, wid = t >> 6;
        for (int i = t; i < 4096; i += 256) Wl[i & 63][i >> 6] = W[i];
        int nrem = min(64, N_NODES - nstart);
        for (int i = t; i < nrem * 16; i += 256)
            ((float4*)hL)[i] = ((const float4*)(emb + (size_t)nstart * EMBED))[i];
        // last GEMV block zeros the dummy pad row g[N_NODES]
        if (gb == GEMV_BLKS - 1 && t < 64) g[(size_t)N_NODES * EMBED + t] = 0;
        __syncthreads();
        for (int n = wid; n < nrem; n += 4) {
            float x = 0.f;
            #pragma unroll
            for (int d = 0; d < 64; ++d)
                x += hL[n][d] * Wl[d][lane];
            g[(size_t)(nstart + n) * EMBED + lane] = f2bf(x);
        }
    }
}

// ---- dense GEMV (fp32 in, bf16 out; layer 2); pad row untouched (stays 0) ----
__global__ __launch_bounds__(256) void gemv_kernel(const float* __restrict__ h,
                                                   const float* __restrict__ W,
                                                   unsigned short* __restrict__ g) {
    __shared__ float hL[64][64];
    __shared__ float Wl[64][65];
    int t = threadIdx.x;
    int nstart = blockIdx.x * 64;
    int lane = t & 63, wid = t >> 6;
    for (int i = t; i < 4096; i += 256) Wl[i & 63][i >> 6] = W[i];
    int nrem = min(64, N_NODES - nstart);
    for (int i = t; i < nrem * 16; i += 256)
        ((float4*)hL)[i] = ((const float4*)(h + (size_t)nstart * EMBED))[i];
    __syncthreads();
    for (int n = wid; n < nrem; n += 4) {
        float x = 0.f;
        #pragma unroll
        for (int d = 0; d < 64; ++d)
            x += hL[n][d] * Wl[d][lane];
        g[(size_t)(nstart + n) * EMBED + lane] = f2bf(x);
    }
}

// ---- gather-mean + bias + tanh; wave per node; branch-free, bf16 g rows (2 lines),
//      16-slot main loop (4 gathers in flight) + 4-slot tail ----
__global__ __launch_bounds__(256) void agg_kernel(const unsigned short* __restrict__ g,
                                                  const float* __restrict__ bias,
                                                  const int* __restrict__ rowp,
                                                  const int* __restrict__ degv,
                                                  const int* __restrict__ col,
                                                  float* __restrict__ hout) {
    int t = threadIdx.x;
    int wid = t >> 6, lane = t & 63;
    int node = blockIdx.x * 4 + wid;   // grid exactly N_NODES/4
    int gg = lane >> 4, d16 = lane & 15;
    int start = rowp[node];
    int dg = degv[node];
    int pcnt = (dg + 3) & ~3;
    int endp = start + pcnt;
    float4 bb = ((const float4*)bias)[d16];
    float4 acc = {0.f, 0.f, 0.f, 0.f};
    int e = start;
    for (; e + 16 <= endp; e += 16) {      // 4 row-gathers in flight
        int s0 = col[e + gg];
        int s1 = col[e + 4 + gg];
        int s2 = col[e + 8 + gg];
        int s3 = col[e + 12 + gg];
        ushort4 v0 = ((const ushort4*)(g + (size_t)s0 * EMBED))[d16];
        ushort4 v1 = ((const ushort4*)(g + (size_t)s1 * EMBED))[d16];
        ushort4 v2 = ((const ushort4*)(g + (size_t)s2 * EMBED))[d16];
        ushort4 v3 = ((const ushort4*)(g + (size_t)s3 * EMBED))[d16];
        acc.x += (bf2f(v0.x) + bf2f(v1.x)) + (bf2f(v2.x) + bf2f(v3.x));
        acc.y += (bf2f(v0.y) + bf2f(v1.y)) + (bf2f(v2.y) + bf2f(v3.y));
        acc.z += (bf2f(v0.z) + bf2f(v1.z)) + (bf2f(v2.z) + bf2f(v3.z));
        acc.w += (bf2f(v0.w) + bf2f(v1.w)) + (bf2f(v2.w) + bf2f(v3.w));
    }
    for (; e < endp; e += 4) {             // 4-slot tail (0..3 iterations)
        int s0 = col[e + gg];
        ushort4 v0 = ((const ushort4*)(g + (size_t)s0 * EMBED))[d16];
        acc.x += bf2f(v0.x);
        acc.y += bf2f(v0.y);
        acc.z += bf2f(v0.z);
        acc.w += bf2f(v0.w);
    }
    #pragma unroll
    for (int off = 16; off < 64; off <<= 1) {
        acc.x += __shfl_xor(acc.x, off);
        acc.y += __shfl_xor(acc.y, off);
        acc.z += __shfl_xor(acc.z, off);
        acc.w += __shfl_xor(acc.w, off);
    }
    float inv = (dg > 0) ? 1.0f / (float)dg : 0.f;
    if (gg == 0) {
        float4 o;
        o.x = tanhf(acc.x * inv + bb.x);
        o.y = tanhf(acc.y * inv + bb.y);
        o.z = tanhf(acc.z * inv + bb.z);
        o.w = tanhf(acc.w * inv + bb.w);
        ((float4*)(hout + (size_t)node * EMBED))[d16] = o;
    }
}

// ---- pair scoring: 16 lanes x float4 per pair ----
__global__ __launch_bounds__(256) void score_kernel(const float* __restrict__ h,
                                                    const int* __restrict__ ui,
                                                    const int* __restrict__ ii,
                                                    float* __restrict__ out) {
    int t = threadIdx.x;
    int idx = blockIdx.x * 16 + (t >> 4);
    int d16 = t & 15;
    int u = ui[idx];
    int v = ii[idx];
    float4 a = ((const float4*)(h + (size_t)u * EMBED))[d16];
    float4 b = ((const float4*)(h + (size_t)v * EMBED))[d16];
    float p = a.x * b.x + a.y * b.y + a.z * b.z + a.w * b.w;
    #pragma unroll
    for (int off = 8; off > 0; off >>= 1)
        p += __shfl_xor(p, off);
    if (d16 == 0) out[idx] = p;
}

extern "C" void kernel_launch(void* const* d_in, const int* in_sizes, int n_in,
                              void* d_out, int out_size, void* d_ws, size_t ws_size,
                              hipStream_t stream) {
    const float* emb = (const float*)d_in[0];
    const float* W0  = (const float*)d_in[1];
    const float* b0  = (const float*)d_in[2];
    const float* W1  = (const float*)d_in[3];
    const float* b1  = (const float*)d_in[4];
    const int* src   = (const int*)d_in[5];
    const int* dst   = (const int*)d_in[6];
    const int* ui    = (const int*)d_in[7];
    const int* ii    = (const int*)d_in[8];
    float* out = (float*)d_out;

    char* p = (char*)d_ws;
    auto alloc = [&](size_t bytes) {
        char* r = p;
        p += (bytes + 255) & ~(size_t)255;
        return r;
    };
    int* counts          = (int*)alloc(sizeof(int) * NBUCK * CB);
    int* offs            = (int*)alloc(sizeof(int) * NBUCK * CB);
    int* btot            = (int*)alloc(sizeof(int) * NBUCK);
    int* base            = (int*)alloc(sizeof(int) * (NBUCK + 1));
    int* rowp            = (int*)alloc(sizeof(int) * N_NODES);
    int* degv            = (int*)alloc(sizeof(int) * N_NODES);
    unsigned* pairs      = (unsigned*)alloc(sizeof(unsigned) * N_EDGES);
    int* col             = (int*)alloc(sizeof(int) * NBUCK * CAP);
    unsigned short* gbuf = (unsigned short*)alloc(sizeof(unsigned short) * (N_NODES + 1) * EMBED);
    float* hbuf          = (float*)alloc(sizeof(float) * N_NODES * EMBED);

    hipMemsetAsync(btot, 0, sizeof(int) * NBUCK, stream);
    hist_kernel<<<CB, 1024, 0, stream>>>(dst, counts, btot);
    bscan_kernel<<<1, 512, 0, stream>>>(btot, base);
    offs_kernel<<<NBUCK, 64, 0, stream>>>(counts, base, offs);
    scatter_kernel<<<CB, 1024, 0, stream>>>(src, dst, offs, pairs);
    // bucketsort (391 blocks, padded col) overlapped with layer-1 GEMV (782 blocks)
    sortgemv_kernel<<<NBUCK + GEMV_BLKS, 256, 0, stream>>>(pairs, base, rowp, degv, col,
                                                           emb, W0, gbuf);
    agg_kernel<<<N_NODES / 4, 256, 0, stream>>>(gbuf, b0, rowp, degv, col, hbuf);
    gemv_kernel<<<GEMV_BLKS, 256, 0, stream>>>(hbuf, W1, gbuf);
    agg_kernel<<<N_NODES / 4, 256, 0, stream>>>(gbuf, b1, rowp, degv, col, hbuf);
    score_kernel<<<N_PAIRS / 16, 256, 0, stream>>>(hbuf, ui, ii, out);
}

// Round 14
// 210.072 us; speedup vs baseline: 1.8491x; 1.0504x over previous
//
#include <hip/hip_runtime.h>

#define N_NODES 50000
#define N_EDGES 1250000
#define EMBED 64
#define N_PAIRS (1024 * 100)
#define BSHIFT 7
#define BSIZE 128
#define NBUCK 391      // ceil(50000/128)
#define CB 153         // edge blocks (8192 edges each)
#define FAST_MAX 3584  // fast path: padded total <=4096 (bucket mean 3200, sd 57)
#define CAP 4096       // per-bucket col capacity (padded, bucket-strided)
#define GEMV_BLKS ((N_NODES + 63) / 64)   // 782

__device__ inline float bf2f(unsigned short u) {
    return __uint_as_float(((unsigned)u) << 16);
}
__device__ inline unsigned short f2bf(float x) {
    unsigned u = __float_as_uint(x);
    u += 0x7FFF + ((u >> 16) & 1);   // round-to-nearest-even
    return (unsigned short)(u >> 16);
}

// ---- pass 1: per-block bucket histogram; counts[bucket][block] + global bucket totals ----
__global__ __launch_bounds__(1024) void hist_kernel(const int* __restrict__ dst,
                                                    int* __restrict__ counts,
                                                    int* __restrict__ btot) {
    __shared__ int hl[NBUCK];
    int t = threadIdx.x, b = blockIdx.x;
    for (int i = t; i < NBUCK; i += 1024) hl[i] = 0;
    __syncthreads();
    #pragma unroll
    for (int rep = 0; rep < 2; ++rep) {
        int i4 = b * 2048 + rep * 1024 + t;
        if (i4 < N_EDGES / 4) {
            int4 d = ((const int4*)dst)[i4];
            atomicAdd(&hl[d.x >> BSHIFT], 1);
            atomicAdd(&hl[d.y >> BSHIFT], 1);
            atomicAdd(&hl[d.z >> BSHIFT], 1);
            atomicAdd(&hl[d.w >> BSHIFT], 1);
        }
    }
    __syncthreads();
    for (int i = t; i < NBUCK; i += 1024) {
        int v = hl[i];
        counts[i * CB + b] = v;
        if (v) atomicAdd(&btot[i], v);
    }
}

// ---- pass 2a (1 small block): scan 391 bucket totals -> base[] ----
__global__ __launch_bounds__(512) void bscan_kernel(const int* __restrict__ btot,
                                                    int* __restrict__ base) {
    __shared__ int ws[8];
    int t = threadIdx.x, lane = t & 63, wid = t >> 6;
    int v = (t < NBUCK) ? btot[t] : 0;
    int incl = v;
    #pragma unroll
    for (int off = 1; off < 64; off <<= 1) {
        int o = __shfl_up(incl, off);
        if (lane >= off) incl += o;
    }
    if (lane == 63) ws[wid] = incl;
    __syncthreads();
    if (t < 8) {
        int x = ws[t];
        #pragma unroll
        for (int off = 1; off < 8; off <<= 1) {
            int o = __shfl_up(x, off);
            if (t >= off) x += o;
        }
        ws[t] = x;
    }
    __syncthreads();
    int ex = ((wid > 0) ? ws[wid - 1] : 0) + incl - v;
    if (t < NBUCK) base[t] = ex;
    if (t == 0) base[NBUCK] = N_EDGES;
}

// ---- pass 2b: per-bucket wave-scan of its contiguous count row -> offs ----
__global__ __launch_bounds__(64) void offs_kernel(const int* __restrict__ counts,
                                                  const int* __restrict__ base,
                                                  int* __restrict__ offs) {
    int k = blockIdx.x, lane = threadIdx.x;
    const int* rowp = counts + (size_t)k * CB;
    int* orow = offs + (size_t)k * CB;
    int carry = base[k];
    #pragma unroll
    for (int tile = 0; tile < 3; ++tile) {
        int b = tile * 64 + lane;
        int v = (b < CB) ? rowp[b] : 0;
        int incl = v;
        #pragma unroll
        for (int off = 1; off < 64; off <<= 1) {
            int o = __shfl_up(incl, off);
            if (lane >= off) incl += o;
        }
        if (b < CB) orow[b] = carry + incl - v;
        carry += __shfl(incl, 63);
    }
}

// ---- pass 3: scatter edges into bucket-grouped pairs (LDS cursors) ----
__global__ __launch_bounds__(1024) void scatter_kernel(const int* __restrict__ src,
                                                       const int* __restrict__ dst,
                                                       const int* __restrict__ offs,
                                                       unsigned int* __restrict__ pairs) {
    __shared__ int cur[NBUCK];
    int t = threadIdx.x, b = blockIdx.x;
    for (int i = t; i < NBUCK; i += 1024) cur[i] = offs[i * CB + b];
    __syncthreads();
    #pragma unroll
    for (int rep = 0; rep < 2; ++rep) {
        int i4 = b * 2048 + rep * 1024 + t;
        if (i4 < N_EDGES / 4) {
            int4 s4 = ((const int4*)src)[i4];
            int4 d4 = ((const int4*)dst)[i4];
            int p;
            p = atomicAdd(&cur[d4.x >> BSHIFT], 1);
            pairs[p] = ((unsigned)(d4.x & (BSIZE - 1)) << 16) | (unsigned)s4.x;
            p = atomicAdd(&cur[d4.y >> BSHIFT], 1);
            pairs[p] = ((unsigned)(d4.y & (BSIZE - 1)) << 16) | (unsigned)s4.y;
            p = atomicAdd(&cur[d4.z >> BSHIFT], 1);
            pairs[p] = ((unsigned)(d4.z & (BSIZE - 1)) << 16) | (unsigned)s4.z;
            p = atomicAdd(&cur[d4.w >> BSHIFT], 1);
            pairs[p] = ((unsigned)(d4.w & (BSIZE - 1)) << 16) | (unsigned)s4.w;
        }
    }
}

// ---- pass 4 (heterogeneous): blocks 0..NBUCK-1 = per-bucket sort -> PADDED col
//      + rowp[] + degv[]; blocks NBUCK.. = dense GEMV g1 = emb @ W0^T (bf16 out),
//      last GEMV block zeros pad row g1[N_NODES]. ----
#define SMEM_BYTES 34832
__global__ __launch_bounds__(256) void sortgemv_kernel(const unsigned int* __restrict__ pairs,
                                                       const int* __restrict__ base,
                                                       int* __restrict__ rowp,
                                                       int* __restrict__ degv,
                                                       int* __restrict__ col,
                                                       const float* __restrict__ emb,
                                                       const float* __restrict__ W,
                                                       unsigned short* __restrict__ g) {
    __shared__ __align__(16) char smem[SMEM_BYTES];
    int t = threadIdx.x;
    if (blockIdx.x < NBUCK) {
        // ---------------- bucketsort path ----------------
        unsigned* ebuf = (unsigned*)smem;             // 16KB
        int* staged    = (int*)(smem + 16384);        // 16KB
        int* hist      = (int*)(smem + 32768);        // 512B
        int* cur       = (int*)(smem + 33280);        // 512B
        int* wtot      = (int*)(smem + 33792);
        int* ptotS     = (int*)(smem + 33796);
        int k = blockIdx.x;
        int lane = t & 63, wid = t >> 6;
        int nstart = k * BSIZE;
        int nodes = min(BSIZE, N_NODES - nstart);
        int estart = base[k], eend = base[k + 1];
        int cnt = eend - estart;
        int cbase = k << 12;   // k * CAP
        if (t < BSIZE) hist[t] = 0;
        __syncthreads();
        if (cnt <= FAST_MAX) {
            for (int i = t; i < cnt; i += 256) {
                unsigned w = pairs[estart + i];
                ebuf[i] = w;
                atomicAdd(&hist[w >> 16], 1);
            }
            __syncthreads();
            if (t < BSIZE) {                 // padded scan over 128 counters
                int dgv = hist[t];
                int pd = (dgv + 3) & ~3;     // pad row to multiple of 4
                int incl = pd;
                #pragma unroll
                for (int off = 1; off < 64; off <<= 1) {
                    int o = __shfl_up(incl, off);
                    if (lane >= off) incl += o;
                }
                if (t == 63) *wtot = incl;
                __syncthreads();
                int ex = incl - pd + ((wid == 1) ? *wtot : 0);
                cur[t] = ex;
                if (t == BSIZE - 1) *ptotS = ex + pd;
                if (t < nodes) {
                    rowp[nstart + t] = cbase + ex;
                    degv[nstart + t] = dgv;
                }
            } else {
                __syncthreads();
            }
            __syncthreads();
            int ptot = *ptotS;
            for (int i = t; i < ptot; i += 256) staged[i] = N_NODES;  // dummy init
            __syncthreads();
            for (int i = t; i < cnt; i += 256) {
                unsigned w = ebuf[i];
                int pos = atomicAdd(&cur[w >> 16], 1);
                staged[pos] = (int)(w & 0xFFFFu);
            }
            __syncthreads();
            for (int i = t; i < ptot; i += 256) col[cbase + i] = staged[i];
        } else {   // statistically unreachable fallback
            for (int i = t; i < cnt; i += 256)
                atomicAdd(&hist[pairs[estart + i] >> 16], 1);
            __syncthreads();
            if (t < BSIZE) {
                int dgv = hist[t];
                int pd = (dgv + 3) & ~3;
                int incl = pd;
                #pragma unroll
                for (int off = 1; off < 64; off <<= 1) {
                    int o = __shfl_up(incl, off);
                    if (lane >= off) incl += o;
                }
                if (t == 63) *wtot = incl;
                __syncthreads();
                int ex = incl - pd + ((wid == 1) ? *wtot : 0);
                cur[t] = ex;
                if (t == BSIZE - 1) *ptotS = ex + pd;
                if (t < nodes) {
                    rowp[nstart + t] = cbase + ex;
                    degv[nstart + t] = dgv;
                }
            } else {
                __syncthreads();
            }
            __syncthreads();
            int ptot = *ptotS;
            for (int i = t; i < ptot; i += 256) col[cbase + i] = N_NODES;
            __syncthreads();
            for (int i = t; i < cnt; i += 256) {
                unsigned w = pairs[estart + i];
                int pos = atomicAdd(&cur[w >> 16], 1);
                col[cbase + pos] = (int)(w & 0xFFFFu);
            }
        }
    } else {
        // ---------------- dense GEMV path (fp32 in, bf16 out) ----------------
        float (*hL)[64] = (float (*)[64])smem;            // 16KB
        float (*Wl)[65] = (float (*)[65])(smem + 16384);  // 16.6KB
        int gb = blockIdx.x - NBUCK;
        int nstart = gb * 64;
        int lane = t & 63, wid = t >> 6;
        for (int i = t; i < 4096; i += 256) Wl[i & 63][i >> 6] = W[i];
        int nrem = min(64, N_NODES - nstart);
        for (int i = t; i < nrem * 16; i += 256)
            ((float4*)hL)[i] = ((const float4*)(emb + (size_t)nstart * EMBED))[i];
        // last GEMV block zeros the dummy pad row g1[N_NODES]
        if (gb == GEMV_BLKS - 1 && t < 64) g[(size_t)N_NODES * EMBED + t] = 0;
        __syncthreads();
        for (int n = wid; n < nrem; n += 4) {
            float x = 0.f;
            #pragma unroll
            for (int d = 0; d < 64; ++d)
                x += hL[n][d] * Wl[d][lane];
            g[(size_t)(nstart + n) * EMBED + lane] = f2bf(x);
        }
    }
}

// ---- layer-1 fused: gather-mean(g1) + bias + tanh -> h1 row (in LDS) -> GEMV with W1
//      -> g2 bf16. h1 never touches global memory. ----
__global__ __launch_bounds__(256) void agg_gemv_kernel(const unsigned short* __restrict__ g,
                                                       const float* __restrict__ bias,
                                                       const float* __restrict__ W,   // W1
                                                       const int* __restrict__ rowp,
                                                       const int* __restrict__ degv,
                                                       const int* __restrict__ col,
                                                       unsigned short* __restrict__ g2) {
    __shared__ float Wl[64][65];    // Wl[d][j] = W[j][d]
    __shared__ float rowL[4][64];   // per-wave h1 row
    int t = threadIdx.x;
    int wid = t >> 6, lane = t & 63;
    for (int i = t; i < 4096; i += 256) Wl[i & 63][i >> 6] = W[i];
    int node = blockIdx.x * 4 + wid;   // grid exactly N_NODES/4
    // block 0 also zeros the g2 pad row (read by agg_out's dummy gathers)
    if (blockIdx.x == 0 && t < 64) g2[(size_t)N_NODES * EMBED + t] = 0;
    int gg = lane >> 4, d16 = lane & 15;
    int start = rowp[node];
    int dg = degv[node];
    int pcnt = (dg + 3) & ~3;
    int endp = start + pcnt;
    float4 bb = ((const float4*)bias)[d16];
    float4 acc = {0.f, 0.f, 0.f, 0.f};
    int e = start;
    for (; e + 16 <= endp; e += 16) {      // 4 row-gathers in flight
        int s0 = col[e + gg];
        int s1 = col[e + 4 + gg];
        int s2 = col[e + 8 + gg];
        int s3 = col[e + 12 + gg];
        ushort4 v0 = ((const ushort4*)(g + (size_t)s0 * EMBED))[d16];
        ushort4 v1 = ((const ushort4*)(g + (size_t)s1 * EMBED))[d16];
        ushort4 v2 = ((const ushort4*)(g + (size_t)s2 * EMBED))[d16];
        ushort4 v3 = ((const ushort4*)(g + (size_t)s3 * EMBED))[d16];
        acc.x += (bf2f(v0.x) + bf2f(v1.x)) + (bf2f(v2.x) + bf2f(v3.x));
        acc.y += (bf2f(v0.y) + bf2f(v1.y)) + (bf2f(v2.y) + bf2f(v3.y));
        acc.z += (bf2f(v0.z) + bf2f(v1.z)) + (bf2f(v2.z) + bf2f(v3.z));
        acc.w += (bf2f(v0.w) + bf2f(v1.w)) + (bf2f(v2.w) + bf2f(v3.w));
    }
    for (; e < endp; e += 4) {             // 4-slot tail
        int s0 = col[e + gg];
        ushort4 v0 = ((const ushort4*)(g + (size_t)s0 * EMBED))[d16];
        acc.x += bf2f(v0.x);
        acc.y += bf2f(v0.y);
        acc.z += bf2f(v0.z);
        acc.w += bf2f(v0.w);
    }
    #pragma unroll
    for (int off = 16; off < 64; off <<= 1) {
        acc.x += __shfl_xor(acc.x, off);
        acc.y += __shfl_xor(acc.y, off);
        acc.z += __shfl_xor(acc.z, off);
        acc.w += __shfl_xor(acc.w, off);
    }
    float inv = (dg > 0) ? 1.0f / (float)dg : 0.f;
    if (gg == 0) {
        rowL[wid][d16 * 4 + 0] = tanhf(acc.x * inv + bb.x);
        rowL[wid][d16 * 4 + 1] = tanhf(acc.y * inv + bb.y);
        rowL[wid][d16 * 4 + 2] = tanhf(acc.z * inv + bb.z);
        rowL[wid][d16 * 4 + 3] = tanhf(acc.w * inv + bb.w);
    }
    __syncthreads();   // Wl staged + all rowL rows written
    float x = 0.f;     // lane = output feature j
    #pragma unroll
    for (int d = 0; d < 64; ++d)
        x += rowL[wid][d] * Wl[d][lane];   // rowL read = broadcast; Wl row conflict-free
    g2[(size_t)node * EMBED + lane] = f2bf(x);
}

// ---- layer-2: gather-mean(g2) + bias + tanh -> h2 (bf16, for score) ----
__global__ __launch_bounds__(256) void agg_out_kernel(const unsigned short* __restrict__ g,
                                                      const float* __restrict__ bias,
                                                      const int* __restrict__ rowp,
                                                      const int* __restrict__ degv,
                                                      const int* __restrict__ col,
                                                      unsigned short* __restrict__ hout) {
    int t = threadIdx.x;
    int wid = t >> 6, lane = t & 63;
    int node = blockIdx.x * 4 + wid;   // grid exactly N_NODES/4
    int gg = lane >> 4, d16 = lane & 15;
    int start = rowp[node];
    int dg = degv[node];
    int pcnt = (dg + 3) & ~3;
    int endp = start + pcnt;
    float4 bb = ((const float4*)bias)[d16];
    float4 acc = {0.f, 0.f, 0.f, 0.f};
    int e = start;
    for (; e + 16 <= endp; e += 16) {
        int s0 = col[e + gg];
        int s1 = col[e + 4 + gg];
        int s2 = col[e + 8 + gg];
        int s3 = col[e + 12 + gg];
        ushort4 v0 = ((const ushort4*)(g + (size_t)s0 * EMBED))[d16];
        ushort4 v1 = ((const ushort4*)(g + (size_t)s1 * EMBED))[d16];
        ushort4 v2 = ((const ushort4*)(g + (size_t)s2 * EMBED))[d16];
        ushort4 v3 = ((const ushort4*)(g + (size_t)s3 * EMBED))[d16];
        acc.x += (bf2f(v0.x) + bf2f(v1.x)) + (bf2f(v2.x) + bf2f(v3.x));
        acc.y += (bf2f(v0.y) + bf2f(v1.y)) + (bf2f(v2.y) + bf2f(v3.y));
        acc.z += (bf2f(v0.z) + bf2f(v1.z)) + (bf2f(v2.z) + bf2f(v3.z));
        acc.w += (bf2f(v0.w) + bf2f(v1.w)) + (bf2f(v2.w) + bf2f(v3.w));
    }
    for (; e < endp; e += 4) {
        int s0 = col[e + gg];
        ushort4 v0 = ((const ushort4*)(g + (size_t)s0 * EMBED))[d16];
        acc.x += bf2f(v0.x);
        acc.y += bf2f(v0.y);
        acc.z += bf2f(v0.z);
        acc.w += bf2f(v0.w);
    }
    #pragma unroll
    for (int off = 16; off < 64; off <<= 1) {
        acc.x += __shfl_xor(acc.x, off);
        acc.y += __shfl_xor(acc.y, off);
        acc.z += __shfl_xor(acc.z, off);
        acc.w += __shfl_xor(acc.w, off);
    }
    float inv = (dg > 0) ? 1.0f / (float)dg : 0.f;
    if (gg == 0) {
        ushort4 o;
        o.x = f2bf(tanhf(acc.x * inv + bb.x));
        o.y = f2bf(tanhf(acc.y * inv + bb.y));
        o.z = f2bf(tanhf(acc.z * inv + bb.z));
        o.w = f2bf(tanhf(acc.w * inv + bb.w));
        ((ushort4*)(hout + (size_t)node * EMBED))[d16] = o;
    }
}

// ---- pair scoring: 16 lanes x ushort4 (bf16) per pair ----
__global__ __launch_bounds__(256) void score_kernel(const unsigned short* __restrict__ h,
                                                    const int* __restrict__ ui,
                                                    const int* __restrict__ ii,
                                                    float* __restrict__ out) {
    int t = threadIdx.x;
    int idx = blockIdx.x * 16 + (t >> 4);
    int d16 = t & 15;
    int u = ui[idx];
    int v = ii[idx];
    ushort4 a4 = ((const ushort4*)(h + (size_t)u * EMBED))[d16];
    ushort4 b4 = ((const ushort4*)(h + (size_t)v * EMBED))[d16];
    float p = bf2f(a4.x) * bf2f(b4.x) + bf2f(a4.y) * bf2f(b4.y) +
              bf2f(a4.z) * bf2f(b4.z) + bf2f(a4.w) * bf2f(b4.w);
    #pragma unroll
    for (int off = 8; off > 0; off >>= 1)
        p += __shfl_xor(p, off);
    if (d16 == 0) out[idx] = p;
}

extern "C" void kernel_launch(void* const* d_in, const int* in_sizes, int n_in,
                              void* d_out, int out_size, void* d_ws, size_t ws_size,
                              hipStream_t stream) {
    const float* emb = (const float*)d_in[0];
    const float* W0  = (const float*)d_in[1];
    const float* b0  = (const float*)d_in[2];
    const float* W1  = (const float*)d_in[3];
    const float* b1  = (const float*)d_in[4];
    const int* src   = (const int*)d_in[5];
    const int* dst   = (const int*)d_in[6];
    const int* ui    = (const int*)d_in[7];
    const int* ii    = (const int*)d_in[8];
    float* out = (float*)d_out;

    char* p = (char*)d_ws;
    auto alloc = [&](size_t bytes) {
        char* r = p;
        p += (bytes + 255) & ~(size_t)255;
        return r;
    };
    int* counts           = (int*)alloc(sizeof(int) * NBUCK * CB);
    int* offs             = (int*)alloc(sizeof(int) * NBUCK * CB);
    int* btot             = (int*)alloc(sizeof(int) * NBUCK);
    int* base             = (int*)alloc(sizeof(int) * (NBUCK + 1));
    int* rowp             = (int*)alloc(sizeof(int) * N_NODES);
    int* degv             = (int*)alloc(sizeof(int) * N_NODES);
    unsigned* pairs       = (unsigned*)alloc(sizeof(unsigned) * N_EDGES);
    int* col              = (int*)alloc(sizeof(int) * NBUCK * CAP);
    unsigned short* g1buf = (unsigned short*)alloc(sizeof(unsigned short) * (N_NODES + 1) * EMBED);
    unsigned short* g2buf = (unsigned short*)alloc(sizeof(unsigned short) * (N_NODES + 1) * EMBED);
    unsigned short* hbuf  = (unsigned short*)alloc(sizeof(unsigned short) * N_NODES * EMBED);

    hipMemsetAsync(btot, 0, sizeof(int) * NBUCK, stream);
    hist_kernel<<<CB, 1024, 0, stream>>>(dst, counts, btot);
    bscan_kernel<<<1, 512, 0, stream>>>(btot, base);
    offs_kernel<<<NBUCK, 64, 0, stream>>>(counts, base, offs);
    scatter_kernel<<<CB, 1024, 0, stream>>>(src, dst, offs, pairs);
    // bucketsort (391 blocks, padded col) overlapped with layer-1 GEMV (782 blocks)
    sortgemv_kernel<<<NBUCK + GEMV_BLKS, 256, 0, stream>>>(pairs, base, rowp, degv, col,
                                                           emb, W0, g1buf);
    // layer 1 fused with gemv2: h1 stays on-chip
    agg_gemv_kernel<<<N_NODES / 4, 256, 0, stream>>>(g1buf, b0, W1, rowp, degv, col, g2buf);
    // layer 2 -> bf16 h2
    agg_out_kernel<<<N_NODES / 4, 256, 0, stream>>>(g2buf, b1, rowp, degv, col, hbuf);
    score_kernel<<<N_PAIRS / 16, 256, 0, stream>>>(hbuf, ui, ii, out);
}